// Round 6
// baseline (718.190 us; speedup 1.0000x reference)
//
#include <hip/hip_runtime.h>
#include <hip/hip_fp16.h>

// Problem constants (fixed by the reference)
constexpr int NN = 100000;          // nodes
constexpr int EE = 1600000;         // edges (without self loops)
constexpr int ET = EE + NN;         // edges + self loops
constexpr float NEG = 0.2f;

typedef _Float16 f16x8 __attribute__((ext_vector_type(8)));
typedef _Float16 f16x4 __attribute__((ext_vector_type(4)));
typedef float    f32x4 __attribute__((ext_vector_type(4)));

// ---------------------------------------------------------------------------
// CSR build: histogram -> scan -> scatter (csr only; dstv filled sequentially)
// ---------------------------------------------------------------------------
__global__ __launch_bounds__(256) void k_count(const int* __restrict__ ei, int* __restrict__ deg) {
    int i = blockIdx.x * 256 + threadIdx.x;
    if (i >= ET) return;
    int dst = (i < EE) ? ei[EE + i] : (i - EE);
    atomicAdd(&deg[dst], 1);
}

__global__ __launch_bounds__(256) void k_part(const int* __restrict__ deg, int* __restrict__ part) {
    __shared__ int sh[256];
    int i = blockIdx.x * 256 + threadIdx.x;
    sh[threadIdx.x] = (i < NN) ? deg[i] : 0;
    __syncthreads();
    for (int o = 128; o; o >>= 1) {
        if (threadIdx.x < o) sh[threadIdx.x] += sh[threadIdx.x + o];
        __syncthreads();
    }
    if (threadIdx.x == 0) part[blockIdx.x] = sh[0];
}

__global__ __launch_bounds__(512) void k_scanp(int* __restrict__ part, int nb) {
    __shared__ int sh[512];
    int t = threadIdx.x;
    int v = (t < nb) ? part[t] : 0;
    sh[t] = v;
    __syncthreads();
    for (int o = 1; o < 512; o <<= 1) {
        int u = (t >= o) ? sh[t - o] : 0;
        __syncthreads();
        sh[t] += u;
        __syncthreads();
    }
    if (t < nb) part[t] = sh[t] - v;   // exclusive
}

__global__ __launch_bounds__(256) void k_scan(const int* __restrict__ deg, const int* __restrict__ part,
                                              int* __restrict__ rs, int* __restrict__ cur) {
    __shared__ int sh[256];
    int t = threadIdx.x;
    int i = blockIdx.x * 256 + t;
    int v = (i < NN) ? deg[i] : 0;
    sh[t] = v;
    __syncthreads();
    for (int o = 1; o < 256; o <<= 1) {
        int u = (t >= o) ? sh[t - o] : 0;
        __syncthreads();
        sh[t] += u;
        __syncthreads();
    }
    int incl = sh[t];
    int base = part[blockIdx.x];
    if (i < NN) {
        rs[i]  = base + incl - v;
        cur[i] = base + incl - v;
        if (i == NN - 1) rs[NN] = base + incl;
    }
}

__global__ __launch_bounds__(256) void k_scatter(const int* __restrict__ ei, int* __restrict__ cur,
                                                 int* __restrict__ csr) {
    int i = blockIdx.x * 256 + threadIdx.x;
    if (i >= ET) return;
    int src, dst;
    if (i < EE) { src = ei[i]; dst = ei[EE + i]; }
    else        { src = i - EE; dst = i - EE; }
    int pos = atomicAdd(&cur[dst], 1);
    csr[pos] = src;
}

// dstv[j] = v for j in [rs[v], rs[v+1]) — sequential-ish writes, no atomics.
__global__ __launch_bounds__(256) void k_dstfill(const int* __restrict__ rs, int* __restrict__ dstv) {
    int v = blockIdx.x * 256 + threadIdx.x;
    if (v >= NN) return;
    int a = rs[v], b = rs[v + 1];
    for (int j = a; j < b; ++j) dstv[j] = v;
}

// ---------------------------------------------------------------------------
// MFMA GEMM: xp = x @ W (fp16 inputs to matrix core, fp32 accumulate).
// 128 rows/block, K staged in 64-chunks, LDS +8-half padding.
// OUT_MODE 0: packed {p0,p1,g0,g1} per channel pair, row stride 256 halves.
// OUT_MODE 1: plain fp16 row of C halves.
// ---------------------------------------------------------------------------
template <int K, int C, int OUT_MODE, bool SRCF32>
__global__ __launch_bounds__(256) void gemm_mfma(const void* __restrict__ xv, const float* __restrict__ W,
                                                 __half* __restrict__ xp, int n, int set_off) {
    constexpr int KC  = 64;
    constexpr int AST = KC + 8;
    constexpr int NT  = C / 16;
    constexpr int NST = K / KC;
    __shared__ _Float16 a_lds[128 * AST];
    __shared__ _Float16 w_lds[C * AST];

    const int tid  = threadIdx.x;
    const int w    = tid >> 6;
    const int lane = tid & 63;
    const int quad = lane >> 4;
    const int l16  = lane & 15;
    const long r0  = (long)blockIdx.x * 128;

    f32x4 acc[2][NT];
#pragma unroll
    for (int s = 0; s < 2; s++)
#pragma unroll
        for (int t = 0; t < NT; t++) acc[s][t] = (f32x4){0.f, 0.f, 0.f, 0.f};

    for (int st = 0; st < NST; ++st) {
        const int k0 = st * KC;
        for (int i = tid; i < 128 * (KC / 4); i += 256) {
            int r = i / (KC / 4);
            int q = i % (KC / 4);
            long row = r0 + r;
            f16x4 hv = (f16x4){0, 0, 0, 0};
            if (row < n) {
                if (SRCF32) {
                    float4 v = ((const float4*)xv)[row * (K / 4) + (k0 / 4) + q];
                    hv = (f16x4){(_Float16)v.x, (_Float16)v.y, (_Float16)v.z, (_Float16)v.w};
                } else {
                    hv = ((const f16x4*)xv)[row * (K / 4) + (k0 / 4) + q];
                }
            }
            *(f16x4*)&a_lds[r * AST + q * 4] = hv;
        }
        for (int i = tid; i < C * (KC / 4); i += 256) {
            int nn = i / (KC / 4);
            int kq = i % (KC / 4);
            f16x4 hv;
            hv.x = (_Float16)W[(long)(k0 + kq * 4 + 0) * C + nn];
            hv.y = (_Float16)W[(long)(k0 + kq * 4 + 1) * C + nn];
            hv.z = (_Float16)W[(long)(k0 + kq * 4 + 2) * C + nn];
            hv.w = (_Float16)W[(long)(k0 + kq * 4 + 3) * C + nn];
            *(f16x4*)&w_lds[nn * AST + kq * 4] = hv;
        }
        __syncthreads();

#pragma unroll
        for (int ks = 0; ks < KC; ks += 32) {
            f16x8 a0 = *(const f16x8*)&a_lds[(w * 32 + l16) * AST + ks + quad * 8];
            f16x8 a1 = *(const f16x8*)&a_lds[(w * 32 + 16 + l16) * AST + ks + quad * 8];
#pragma unroll
            for (int t = 0; t < NT; t++) {
                f16x8 b = *(const f16x8*)&w_lds[(t * 16 + l16) * AST + ks + quad * 8];
                acc[0][t] = __builtin_amdgcn_mfma_f32_16x16x32_f16(a0, b, acc[0][t], 0, 0, 0);
                acc[1][t] = __builtin_amdgcn_mfma_f32_16x16x32_f16(a1, b, acc[1][t], 0, 0, 0);
            }
        }
        __syncthreads();
    }

#pragma unroll
    for (int sub = 0; sub < 2; sub++) {
        long rb = r0 + w * 32 + sub * 16 + quad * 4;
#pragma unroll
        for (int t = 0; t < NT; t++) {
            int c = t * 16 + l16;
#pragma unroll
            for (int rg = 0; rg < 4; rg++) {
                long row = rb + rg;
                if (row < n) {
                    __half hv = __float2half(acc[sub][t][rg]);
                    if (OUT_MODE == 0)
                        xp[row * 256 + ((c >> 1) << 2) + (c & 1) + set_off] = hv;
                    else
                        xp[row * (long)C + c] = hv;
                }
            }
        }
    }
}

// ---------------------------------------------------------------------------
// Fused attention coefficients for conv1 from packed fp16 xpc.
// ---------------------------------------------------------------------------
__global__ __launch_bounds__(256) void attn1_fused(const __half2* __restrict__ xpc,
                                                   const float* __restrict__ as_w, const float* __restrict__ ad_w,
                                                   float2* __restrict__ att_s, float2* __restrict__ att_d, int n) {
    int idx = blockIdx.x * 256 + threadIdx.x;
    if (idx >= n * 4) return;
    int v = idx >> 2, hh = idx & 3;
    const __half2* row = xpc + (long)v * 128 + hh * 32;
    const float* a1 = as_w + hh * 32;
    const float* a2 = ad_w + hh * 32;
    float sp1 = 0.f, sp2 = 0.f, sg1 = 0.f, sg2 = 0.f;
#pragma unroll
    for (int t = 0; t < 16; t++) {
        float2 fp = __half22float2(row[2 * t]);
        float2 fg = __half22float2(row[2 * t + 1]);
        float2 w1 = *(const float2*)(a1 + 2 * t);
        float2 w2 = *(const float2*)(a2 + 2 * t);
        sp1 += fp.x * w1.x + fp.y * w1.y;
        sp2 += fp.x * w2.x + fp.y * w2.y;
        sg1 += fg.x * w1.x + fg.y * w1.y;
        sg2 += fg.x * w2.x + fg.y * w2.y;
    }
    att_s[idx] = make_float2(sp1, sg1);
    att_d[idx] = make_float2(sp2, sg2);
}

// attention for conv2 (H=1, C=64), fp16 xp
__global__ __launch_bounds__(256) void attn2_kernel(const __half2* __restrict__ xp,
                                                    const float* __restrict__ as_w, const float* __restrict__ ad_w,
                                                    float* __restrict__ asrc, float* __restrict__ adst, int n) {
    int v = blockIdx.x * 256 + threadIdx.x;
    if (v >= n) return;
    const __half2* p = xp + (long)v * 32;
    float s1 = 0.f, s2 = 0.f;
#pragma unroll
    for (int c = 0; c < 32; c++) {
        float2 xv = __half22float2(p[c]);
        float2 w1 = *(const float2*)(as_w + 2 * c);
        float2 w2 = *(const float2*)(ad_w + 2 * c);
        s1 += xv.x * w1.x + xv.y * w1.y;
        s2 += xv.x * w2.x + xv.y * w2.y;
    }
    asrc[v] = s1;
    adst[v] = s2;
}

// ---------------------------------------------------------------------------
// Per-edge exp-weight precompute for conv1 -> fp16, interleaved
// {p0,g0,p1,g1,p2,g2,p3,g3} (16 B/edge). Pair (p_h,g_h) = half2 at index h.
// ---------------------------------------------------------------------------
__global__ __launch_bounds__(256) void w1prep(const int* __restrict__ csr, const int* __restrict__ dstv,
                                              const float4* __restrict__ att_s4, const float4* __restrict__ att_d4,
                                              f16x8* __restrict__ wb) {
    int j = blockIdx.x * 256 + threadIdx.x;
    if (j >= ET) return;
    int s = csr[j], v = dstv[j];
    float4 s0 = att_s4[s * 2], s1 = att_s4[s * 2 + 1];
    float4 d0 = att_d4[v * 2], d1 = att_d4[v * 2 + 1];
    auto w = [](float e) { e = (e > 0.f) ? e : NEG * e; return __expf(e); };
    f16x8 o;
    o[0] = (_Float16)w(s0.x + d0.x); o[1] = (_Float16)w(s0.y + d0.y);   // h0: p,g
    o[2] = (_Float16)w(s0.z + d0.z); o[3] = (_Float16)w(s0.w + d0.w);   // h1: p,g
    o[4] = (_Float16)w(s1.x + d1.x); o[5] = (_Float16)w(s1.y + d1.y);   // h2: p,g
    o[6] = (_Float16)w(s1.z + d1.z); o[7] = (_Float16)w(s1.w + d1.w);   // h3: p,g
    wb[j] = o;
}

// Per-edge exp-weight for conv2 (H=1): 4 B/edge.
__global__ __launch_bounds__(256) void w2prep(const int* __restrict__ csr, const int* __restrict__ dstv,
                                              const float* __restrict__ asrc, const float* __restrict__ adst,
                                              float* __restrict__ w2b) {
    int j = blockIdx.x * 256 + threadIdx.x;
    if (j >= ET) return;
    float e = asrc[csr[j]] + adst[dstv[j]];
    e = (e > 0.f) ? e : NEG * e;
    w2b[j] = __expf(e);
}

// ---------------------------------------------------------------------------
// Fused single-pass conv1 edge kernel. One wave per dst node; lane l carries
// channels {2l,2l+1} of both sets via ONE 8B gather. fp16 weights (4B read
// per 16-lane group). 8-wide main loop + serial tail (no wasted slots).
// ---------------------------------------------------------------------------
__global__ __launch_bounds__(256) void conv1_edge_fused(const int* __restrict__ rs, const int* __restrict__ csr,
                                                        const uint2* __restrict__ xpc,
                                                        const __half2* __restrict__ wb,   // [edge][head] interleaved
                                                        const float* __restrict__ bias,
                                                        __half* __restrict__ out) {
    int v = blockIdx.x * 4 + (threadIdx.x >> 6);
    if (v >= NN) return;
    int lane = threadIdx.x & 63;
    int e0 = __builtin_amdgcn_readfirstlane(rs[v]);
    int e1 = __builtin_amdgcn_readfirstlane(rs[v + 1]);
    int c0 = lane * 2;
    int h0 = lane >> 4;

    float ap0 = 0.f, ap1 = 0.f, ag0 = 0.f, ag1 = 0.f;
    float dp = 0.f, dg = 0.f;

    auto process = [&](__half2 wh, uint2 r) {
        float2 wv = __half22float2(wh);
        dp += wv.x; dg += wv.y;
        float2 fp = __half22float2(*(__half2*)&r.x);
        float2 fg = __half22float2(*(__half2*)&r.y);
        ap0 += wv.x * fp.x; ap1 += wv.x * fp.y;
        ag0 += wv.y * fg.x; ag1 += wv.y * fg.y;
    };

    int j = e0;
    for (; j + 7 < e1; j += 8) {
        int s[8];
#pragma unroll
        for (int q = 0; q < 8; q++) s[q] = csr[j + q];
        __half2 wv[8];
#pragma unroll
        for (int q = 0; q < 8; q++) wv[q] = wb[(j + q) * 4 + h0];
        uint2 r[8];
#pragma unroll
        for (int q = 0; q < 8; q++) r[q] = xpc[(long)s[q] * 64 + lane];
#pragma unroll
        for (int q = 0; q < 8; q++) process(wv[q], r[q]);
    }
    for (; j < e1; ++j) {
        __half2 wv = wb[j * 4 + h0];
        uint2 r = xpc[(long)csr[j] * 64 + lane];
        process(wv, r);
    }

    float ivp = 1.0f / dp, ivg = 1.0f / dg;
    float b0 = bias[c0], b1v = bias[c0 + 1];
    __half* o = out + (long)v * 256;
    o[c0]           = __float2half(fmaxf(ap0 * ivp + b0, 0.f));
    o[c0 + 1]       = __float2half(fmaxf(ap1 * ivp + b1v, 0.f));
    o[128 + c0]     = __float2half(fmaxf(ag0 * ivg + b0, 0.f));
    o[128 + c0 + 1] = __float2half(fmaxf(ag1 * ivg + b1v, 0.f));
}

// ---------------------------------------------------------------------------
// conv2 edge kernel (H=1, C=64, fp16 xp): 2 edges per wave-trip.
// Lanes 0-31 <-> edge j, lanes 32-63 <-> edge j+1; each lane loads half2
// (channels 2*(lane&31), +1). Final __shfl_xor(32) combine. 8 trips (16
// edges) unrolled in the main loop; pair + odd-edge tails.
// ---------------------------------------------------------------------------
__global__ __launch_bounds__(256) void conv2_edge(const int* __restrict__ rs, const int* __restrict__ csr,
                                                  const __half2* __restrict__ xp,   // row = 32 half2
                                                  const float* __restrict__ w2b,
                                                  const float* __restrict__ bias,
                                                  float* __restrict__ out) {
    int v = blockIdx.x * 4 + (threadIdx.x >> 6);
    if (v >= NN) return;
    int lane = threadIdx.x & 63;
    int half = lane >> 5;
    int l32  = lane & 31;
    int e0 = __builtin_amdgcn_readfirstlane(rs[v]);
    int e1 = __builtin_amdgcn_readfirstlane(rs[v + 1]);

    float ax = 0.f, ay = 0.f, d = 0.f;
    auto process = [&](float w, __half2 xh) {
        float2 f = __half22float2(xh);
        d += w;
        ax += w * f.x; ay += w * f.y;
    };

    int j = e0;
    for (; j + 15 < e1; j += 16) {
        int s[8];
        float w[8];
        __half2 x[8];
#pragma unroll
        for (int q = 0; q < 8; q++) { int jj = j + 2 * q + half; s[q] = csr[jj]; }
#pragma unroll
        for (int q = 0; q < 8; q++) { int jj = j + 2 * q + half; w[q] = w2b[jj]; }
#pragma unroll
        for (int q = 0; q < 8; q++) x[q] = xp[(long)s[q] * 32 + l32];
#pragma unroll
        for (int q = 0; q < 8; q++) process(w[q], x[q]);
    }
    for (; j + 1 < e1; j += 2) {
        int jj = j + half;
        float w = w2b[jj];
        __half2 x = xp[(long)csr[jj] * 32 + l32];
        process(w, x);
    }
    if (j < e1 && half == 0) {
        float w = w2b[j];
        __half2 x = xp[(long)csr[j] * 32 + l32];
        process(w, x);
    }

    d  += __shfl_xor(d, 32, 64);
    ax += __shfl_xor(ax, 32, 64);
    ay += __shfl_xor(ay, 32, 64);

    if (half == 0) {
        float iv = 1.0f / d;
        int c0 = l32 * 2;
        ((float2*)(out + (long)v * 64))[l32] =
            make_float2(ax * iv + bias[c0], ay * iv + bias[c0 + 1]);
    }
}

// ---------------------------------------------------------------------------
// Launch
// ---------------------------------------------------------------------------
extern "C" void kernel_launch(void* const* d_in, const int* in_sizes, int n_in,
                              void* d_out, int out_size, void* d_ws, size_t ws_size,
                              hipStream_t stream) {
    const float* x_ppi = (const float*)d_in[0];
    const float* x_go  = (const float*)d_in[1];
    const int*   ei    = (const int*)d_in[2];
    const float* W1    = (const float*)d_in[3];
    const float* as1   = (const float*)d_in[4];
    const float* ad1   = (const float*)d_in[5];
    const float* b1    = (const float*)d_in[6];
    const float* W2    = (const float*)d_in[7];
    const float* as2   = (const float*)d_in[8];
    const float* ad2   = (const float*)d_in[9];
    const float* b2    = (const float*)d_in[10];
    float* out = (float*)d_out;

    char* ws = (char*)d_ws;
    size_t off = 0;
    auto alloc = [&](size_t bytes) -> void* {
        void* p = ws + off;
        off = (off + bytes + 255) & ~(size_t)255;
        return p;
    };
    int* deg     = (int*)alloc((size_t)NN * 4);
    int* rs      = (int*)alloc((size_t)(NN + 1) * 4);
    int* cur     = (int*)alloc((size_t)NN * 4);
    int* part    = (int*)alloc(512 * 4);
    int* csr     = (int*)alloc((size_t)ET * 4);
    int* dstv    = (int*)alloc((size_t)ET * 4);
    __half* xpc  = (__half*)alloc((size_t)NN * 256 * 2);   // packed {p0,p1,g0,g1} fp16
    __half* xp2  = (__half*)alloc((size_t)NN * 64 * 2);    // conv2 features fp16
    float2* atts = (float2*)alloc((size_t)NN * 4 * 8);
    float2* attd = (float2*)alloc((size_t)NN * 4 * 8);
    float* asr2  = (float*)alloc((size_t)NN * 4);
    float* ads2  = (float*)alloc((size_t)NN * 4);
    __half* wb1  = (__half*)alloc((size_t)ET * 16);        // 8 fp16 weights / edge
    float* w2b   = (float*)alloc((size_t)ET * 4);
    __half* hbuf = (__half*)alloc((size_t)NN * 256 * 2);   // conv1 output, fp16
    (void)ws_size; (void)in_sizes; (void)n_in; (void)out_size;

    const int NB = (NN + 255) / 256;        // 391
    const int EB = (ET + 255) / 256;        // 6641
    const int GB = (NN + 127) / 128;        // 782 (MFMA gemm blocks)

    // CSR build (shared by all three convs)
    hipMemsetAsync(deg, 0, (size_t)NN * 4, stream);
    k_count<<<EB, 256, 0, stream>>>(ei, deg);
    k_part<<<NB, 256, 0, stream>>>(deg, part);
    k_scanp<<<1, 512, 0, stream>>>(part, NB);
    k_scan<<<NB, 256, 0, stream>>>(deg, part, rs, cur);
    k_scatter<<<EB, 256, 0, stream>>>(ei, cur, csr);
    k_dstfill<<<NB, 256, 0, stream>>>(rs, dstv);

    // layer 1: two MFMA GEMMs into packed fp16, fused attn, weight prep, edge conv
    gemm_mfma<128, 128, 0, true><<<GB, 256, 0, stream>>>(x_ppi, W1, xpc, NN, 0);
    gemm_mfma<128, 128, 0, true><<<GB, 256, 0, stream>>>(x_go, W1, xpc, NN, 2);
    attn1_fused<<<(NN * 4 + 255) / 256, 256, 0, stream>>>((const __half2*)xpc, as1, ad1, atts, attd, NN);
    w1prep<<<EB, 256, 0, stream>>>(csr, dstv, (const float4*)atts, (const float4*)attd, (f16x8*)wb1);
    conv1_edge_fused<<<NN / 4, 256, 0, stream>>>(rs, csr, (const uint2*)xpc, (const __half2*)wb1, b1, hbuf);

    // layer 2
    gemm_mfma<256, 64, 1, false><<<GB, 256, 0, stream>>>(hbuf, W2, xp2, NN, 0);
    attn2_kernel<<<(NN + 255) / 256, 256, 0, stream>>>((const __half2*)xp2, as2, ad2, asr2, ads2, NN);
    w2prep<<<EB, 256, 0, stream>>>(csr, dstv, asr2, ads2, w2b);
    conv2_edge<<<NN / 4, 256, 0, stream>>>(rs, csr, (const __half2*)xp2, w2b, b2, out);
}